// Round 9
// baseline (228.254 us; speedup 1.0000x reference)
//
#include <hip/hip_runtime.h>
#include <hip/hip_bf16.h>

// Output layout (floats): Objects[8*20*4] @0 | Object_features[8*20*4096] @640
//                        | valid[8*20] @656000 | fullframe_features[8*4096] @656160
#define OBJ_OFF   0
#define FEAT_OFF  640
#define VALID_OFF 656000
#define FF_OFF    656160

// ws layout: pooled[168*256] f32 | selbox[160*4] f32 | flags[160] f32 | Wb[256*192] bf16
#define POOLED_N  (168 * 256)
#define SELBOX_N  (160 * 4)
#define FLAGS_N   (160)
#define K3        192   // padded K: c*64 + r*8 + q  (r,q in 0..7; r==7 or q==7 -> zero weight)

typedef __attribute__((ext_vector_type(8))) short short8v;
typedef __attribute__((ext_vector_type(4))) short short4v;
typedef __attribute__((ext_vector_type(4))) float f32x4;

__device__ __forceinline__ unsigned int rne_bf16(float f) {
    unsigned int u = __float_as_uint(f);
    return (u + 0x7FFFu + ((u >> 16) & 1u)) >> 16;
}

// ---------------------------------------------------------------------------
// Kernel 0: weights -> bf16 padded layout Wb[oc][k'], k' = c*64 + r*8 + q.
// Also zeroes the pooled accumulator (replaces a memset launch).
// ---------------------------------------------------------------------------
__global__ __launch_bounds__(256) void prep_kernel(
    const float* __restrict__ Wc, unsigned short* __restrict__ Wb,
    float* __restrict__ pooled)
{
    int i = blockIdx.x * 256 + threadIdx.x;     // 192 blocks * 256 = 49152
    if (i < POOLED_N) pooled[i] = 0.f;
    int oc = i / K3, k = i % K3;
    int c = k >> 6, r = (k >> 3) & 7, q = k & 7;
    float v = (r < 7 && q < 7) ? Wc[oc * 147 + c * 49 + r * 7 + q] : 0.f;
    Wb[i] = (unsigned short)rne_bf16(v);
}

// ---------------------------------------------------------------------------
// Kernel 1: per-batch masked top-20 selection (LDS reduction — proven correct)
// ---------------------------------------------------------------------------
__global__ __launch_bounds__(512) void topk_kernel(
    const float* __restrict__ boxes, const float* __restrict__ scores,
    const int* __restrict__ labels, float* __restrict__ d_out,
    float* __restrict__ selbox, float* __restrict__ flags)
{
    __shared__ unsigned long long keys[512];
    __shared__ unsigned long long red[512];
    const int b = blockIdx.x, t = threadIdx.x;

    unsigned long long key = 0ULL;
    if (t < 300) {
        float s = scores[b * 300 + t];
        int   l = labels[b * 300 + t];
        bool cls = (l == 2) || (l == 3) || (l == 4) || (l == 6) || (l == 8);
        if (cls && s > 0.8f) {
            key = ((unsigned long long)__float_as_uint(s) << 32) |
                  (unsigned long long)(unsigned int)(~(unsigned int)t);
        }
    }
    keys[t] = key;
    __syncthreads();

    for (int k = 0; k < 20; ++k) {
        red[t] = keys[t];
        __syncthreads();
        for (int s = 256; s > 0; s >>= 1) {
            if (t < s) red[t] = (red[t] > red[t + s]) ? red[t] : red[t + s];
            __syncthreads();
        }
        unsigned long long m = red[0];
        const int slot = b * 20 + k;
        if (m == 0ULL) {
            if (t == 0) {
                d_out[OBJ_OFF + slot * 4 + 0] = 0.f;
                d_out[OBJ_OFF + slot * 4 + 1] = 0.f;
                d_out[OBJ_OFF + slot * 4 + 2] = 0.f;
                d_out[OBJ_OFF + slot * 4 + 3] = 0.f;
                d_out[VALID_OFF + slot] = 0.f;
                selbox[slot * 4 + 0] = 0.f; selbox[slot * 4 + 1] = 0.f;
                selbox[slot * 4 + 2] = 0.f; selbox[slot * 4 + 3] = 0.f;
                flags[slot] = 0.f;
            }
        } else if (keys[t] == m) {  // unique winner (index embedded in key)
            const float bx0 = boxes[(b * 300 + t) * 4 + 0];
            const float by0 = boxes[(b * 300 + t) * 4 + 1];
            const float bx1 = boxes[(b * 300 + t) * 4 + 2];
            const float by1 = boxes[(b * 300 + t) * 4 + 3];
            d_out[OBJ_OFF + slot * 4 + 0] = bx0;
            d_out[OBJ_OFF + slot * 4 + 1] = by0;
            d_out[OBJ_OFF + slot * 4 + 2] = bx1;
            d_out[OBJ_OFF + slot * 4 + 3] = by1;
            d_out[VALID_OFF + slot] = 1.f;
            selbox[slot * 4 + 0] = bx0; selbox[slot * 4 + 1] = by0;
            selbox[slot * 4 + 2] = bx1; selbox[slot * 4 + 3] = by1;
            bool deg = (bx1 <= bx0) || (by1 <= by0);
            flags[slot] = deg ? 0.f : 1.f;
            keys[t] = 0ULL;
        }
        __syncthreads();
    }
}

// ---------------------------------------------------------------------------
// Compute core with register-resident B fragments (ffconv).
// A-octet (lane l, frag mf, k-step ks): kq=ks*4+lq; c=kq>>3, rr=kq&7;
// 8 contiguous bf16 at tb[c][mf*4+rr][lr*4..+7]. D: col=lr, row=(lq)*4+reg.
// Accumulates ReLU'd per-lane pool partials into poolacc (no atomic here).
// ---------------------------------------------------------------------------
__device__ __forceinline__ void conv_compute_regB(
    const unsigned short (&tb)[3][20][68], const short8v (&breg)[6][4],
    const float (&bias)[4], float (&poolacc)[4], int lr, int lq)
{
    f32x4 acc[4][4];
#pragma unroll
    for (int mf = 0; mf < 4; ++mf)
#pragma unroll
        for (int nf = 0; nf < 4; ++nf)
            acc[mf][nf] = (f32x4){0.f, 0.f, 0.f, 0.f};

#pragma unroll
    for (int ks = 0; ks < 6; ++ks) {
        const int kq = ks * 4 + lq;
        const int c = kq >> 3, rr = kq & 7;
        short8v a[4];
#pragma unroll
        for (int mf = 0; mf < 4; ++mf) {
            const unsigned short* ap = &tb[c][mf * 4 + rr][lr * 4];
            short4v a0 = *(const short4v*)ap;
            short4v a1 = *(const short4v*)(ap + 4);
            a[mf] = __builtin_shufflevector(a0, a1, 0, 1, 2, 3, 4, 5, 6, 7);
        }
#pragma unroll
        for (int mf = 0; mf < 4; ++mf)
#pragma unroll
            for (int nf = 0; nf < 4; ++nf)
                acc[mf][nf] = __builtin_amdgcn_mfma_f32_16x16x32_bf16(
                    a[mf], breg[ks][nf], acc[mf][nf], 0, 0, 0);
    }

#pragma unroll
    for (int nf = 0; nf < 4; ++nf) {
        float s = 0.f;
#pragma unroll
        for (int mf = 0; mf < 4; ++mf)
#pragma unroll
            for (int r = 0; r < 4; ++r) {
                float pv = acc[mf][nf][r] + bias[nf];
                s += pv > 0.f ? pv : 0.f;
            }
        poolacc[nf] += s;
    }
}

// Staging helpers for ffconv: issue all 16 loads (raw) / pack+write later.
__device__ __forceinline__ void ff_stage_issue(
    const float* __restrict__ img, int iy0, int ix0, int tid, float (&sv)[16])
{
#pragma unroll
    for (int it = 0; it < 16; ++it) {
        int i = tid + it * 256;
        float v = 0.f;
        if (i < 4080) {
            int c = i / 1360, rem = i % 1360;
            int ir = rem / 68, icol = rem % 68;
            int gy = iy0 + ir, gx = ix0 + icol;
            if (gy >= 0 && gy < 512 && gx >= 0 && gx < 512)
                v = img[((size_t)c * 512 + gy) * 512 + gx];
        }
        sv[it] = v;
    }
}

__device__ __forceinline__ void ff_stage_write(
    unsigned short (&tb)[3][20][68], int iy0, int ix0, int tid,
    const float (&sv)[16], const float* mean, const float* istd)
{
#pragma unroll
    for (int it = 0; it < 16; ++it) {
        int i = tid + it * 256;
        if (i < 4080) {
            int c = i / 1360, rem = i % 1360;
            int ir = rem / 68, icol = rem % 68;
            int gy = iy0 + ir, gx = ix0 + icol;
            bool inb = (gy >= 0 && gy < 512 && gx >= 0 && gx < 512);
            float nv = inb ? (sv[it] - mean[c]) * istd[c] : 0.f;
            ((unsigned short*)tb)[i] = (unsigned short)rne_bf16(nv);
        }
    }
}

// ---------------------------------------------------------------------------
// Kernel 2: fullframe conv. Block handles T=4 row-tiles (double-buffered LDS,
// async-stage split, reg-B). grid (64 = 8 col-groups x 8 row-blocks, 8 b)
// ---------------------------------------------------------------------------
__global__ __launch_bounds__(256, 2) void ffconv_mfma(
    const float* __restrict__ x, const unsigned short* __restrict__ Wb,
    const float* __restrict__ bc, float* __restrict__ pooled)
{
    __shared__ __align__(16) unsigned short buf[2][3][20][68];
    const int b = blockIdx.y;
    const int tile_x = blockIdx.x & 7, rblk = blockIdx.x >> 3;
    const int tid = threadIdx.x;
    const int w = tid >> 6, l = tid & 63, lr = l & 15, lq = l >> 4;
    const int n0 = w * 64;
    const int ix0 = tile_x * 64 - 1;

    const float mean[3] = {0.485f, 0.456f, 0.406f};
    const float istd[3] = {1.0f / 0.229f, 1.0f / 0.224f, 1.0f / 0.225f};
    const float* __restrict__ img = x + (size_t)b * 3 * 512 * 512;

    short8v breg[6][4];
#pragma unroll
    for (int ks = 0; ks < 6; ++ks)
#pragma unroll
        for (int nf = 0; nf < 4; ++nf)
            breg[ks][nf] = *(const short8v*)&Wb[(size_t)(n0 + nf * 16 + lr) * K3 + ks * 32 + lq * 8];

    float bias[4];
#pragma unroll
    for (int nf = 0; nf < 4; ++nf) bias[nf] = bc[n0 + nf * 16 + lr];

    float poolacc[4] = {0.f, 0.f, 0.f, 0.f};
    float sv[16];

    ff_stage_issue(img, (rblk * 4 + 0) * 16 - 1, ix0, tid, sv);
    ff_stage_write(buf[0], (rblk * 4 + 0) * 16 - 1, ix0, tid, sv, mean, istd);
    __syncthreads();

#pragma unroll
    for (int q = 0; q < 4; ++q) {
        const int cur = q & 1;
        if (q < 3) ff_stage_issue(img, (rblk * 4 + q + 1) * 16 - 1, ix0, tid, sv);
        conv_compute_regB(buf[cur], breg, bias, poolacc, lr, lq);
        if (q < 3)
            ff_stage_write(buf[cur ^ 1], (rblk * 4 + q + 1) * 16 - 1, ix0, tid, sv, mean, istd);
        __syncthreads();
    }

#pragma unroll
    for (int nf = 0; nf < 4; ++nf) {
        float s = poolacc[nf];
        s += __shfl_down(s, 32);
        s += __shfl_down(s, 16);
        if (l < 16) atomicAdd(&pooled[b * 256 + n0 + nf * 16 + lr], s);
    }
}

// ---------------------------------------------------------------------------
// Conv core with B from L2 (cropconv: single tile, reg-B doesn't amortize).
// ---------------------------------------------------------------------------
__device__ __forceinline__ void conv_core(
    const unsigned short (&tile)[3][20][68],
    const unsigned short* __restrict__ Wb, const float* __restrict__ bc,
    float* __restrict__ pooled, int prow, int tid)
{
    const int w = tid >> 6, l = tid & 63;
    const int lr = l & 15, lq = l >> 4;
    const int n0 = w * 64;

    f32x4 acc[4][4];
#pragma unroll
    for (int mf = 0; mf < 4; ++mf)
#pragma unroll
        for (int nf = 0; nf < 4; ++nf)
            acc[mf][nf] = (f32x4){0.f, 0.f, 0.f, 0.f};

#pragma unroll
    for (int ks = 0; ks < 6; ++ks) {
        const int kq = ks * 4 + lq;
        const int c = kq >> 3, rr = kq & 7;
        const int koff = ks * 32 + lq * 8;

        short8v a[4], bfr[4];
#pragma unroll
        for (int mf = 0; mf < 4; ++mf) {
            const unsigned short* ap = &tile[c][mf * 4 + rr][lr * 4];
            short4v a0 = *(const short4v*)ap;
            short4v a1 = *(const short4v*)(ap + 4);
            a[mf] = __builtin_shufflevector(a0, a1, 0, 1, 2, 3, 4, 5, 6, 7);
        }
#pragma unroll
        for (int nf = 0; nf < 4; ++nf)
            bfr[nf] = *(const short8v*)&Wb[(size_t)(n0 + nf * 16 + lr) * K3 + koff];
#pragma unroll
        for (int mf = 0; mf < 4; ++mf)
#pragma unroll
            for (int nf = 0; nf < 4; ++nf)
                acc[mf][nf] = __builtin_amdgcn_mfma_f32_16x16x32_bf16(
                    a[mf], bfr[nf], acc[mf][nf], 0, 0, 0);
    }

#pragma unroll
    for (int nf = 0; nf < 4; ++nf) {
        const int oc = n0 + nf * 16 + lr;
        const float bias = bc[oc];
        float s = 0.f;
#pragma unroll
        for (int mf = 0; mf < 4; ++mf)
#pragma unroll
            for (int r = 0; r < 4; ++r) {
                float pv = acc[mf][nf][r] + bias;
                s += pv > 0.f ? pv : 0.f;
            }
        s += __shfl_down(s, 32);
        s += __shfl_down(s, 16);
        if (l < 16) atomicAdd(&pooled[prow * 256 + oc], s);
    }
}

// ---------------------------------------------------------------------------
// Kernel 3: crop conv. grid 640 = 160 (b,k) x 4 quarters. Batched bilinear
// staging: 2 rounds of 8 elems, 32 loads in flight per round.
// ---------------------------------------------------------------------------
__global__ __launch_bounds__(256, 2) void cropconv_mfma(
    const float* __restrict__ x, const unsigned short* __restrict__ Wb,
    const float* __restrict__ bc, const float* __restrict__ selbox,
    const float* __restrict__ flags, float* __restrict__ pooled)
{
    const int bk = blockIdx.x >> 2, quarter = blockIdx.x & 3;
    if (flags[bk] == 0.f) return;          // features get zeroed anyway
    const int b = bk / 20;
    const int tid = threadIdx.x;

    __shared__ __align__(16) unsigned short tile[3][20][68];

    const float bx0 = selbox[bk * 4 + 0], by0 = selbox[bk * 4 + 1];
    const float bx1 = selbox[bk * 4 + 2], by1 = selbox[bk * 4 + 3];
    const float sy = (by1 - by0) * (1.f / 64.f);
    const float sx = (bx1 - bx0) * (1.f / 64.f);

    const float mean[3] = {0.485f, 0.456f, 0.406f};
    const float istd[3] = {1.0f / 0.229f, 1.0f / 0.224f, 1.0f / 0.225f};
    const float* __restrict__ img = x + (size_t)b * 3 * 512 * 512;

#pragma unroll
    for (int rd = 0; rd < 2; ++rd) {
        float rva[8], rvb[8], rvc[8], rvd[8], rwy[8], rwx[8];
#pragma unroll
        for (int e = 0; e < 8; ++e) {
            int i = tid + (rd * 8 + e) * 256;
            float Ia = 0.f, Ib = 0.f, Ic = 0.f, Id = 0.f, wy = 0.f, wx = 0.f;
            if (i < 4080) {
                int c = i / 1360, rem = i % 1360;
                int ir = rem / 68, icol = rem % 68;
                int cy = quarter * 16 - 1 + ir, cx = icol - 1;
                if (cy >= 0 && cy < 64 && cx >= 0 && cx < 64) {
                    float ys = by0 + ((float)cy + 0.5f) * sy;
                    float xs = bx0 + ((float)cx + 0.5f) * sx;
                    float yf = floorf(ys), xf = floorf(xs);
                    wy = ys - yf; wx = xs - xf;
                    int iy0 = min(max((int)yf, 0), 511), iy1 = min(iy0 + 1, 511);
                    int ix0 = min(max((int)xf, 0), 511), ix1 = min(ix0 + 1, 511);
                    const float* ch = img + (size_t)c * 512 * 512;
                    Ia = ch[iy0 * 512 + ix0]; Ib = ch[iy0 * 512 + ix1];
                    Ic = ch[iy1 * 512 + ix0]; Id = ch[iy1 * 512 + ix1];
                }
            }
            rva[e] = Ia; rvb[e] = Ib; rvc[e] = Ic; rvd[e] = Id;
            rwy[e] = wy; rwx[e] = wx;
        }
#pragma unroll
        for (int e = 0; e < 8; ++e) {
            int i = tid + (rd * 8 + e) * 256;
            if (i < 4080) {
                int c = i / 1360, rem = i % 1360;
                int ir = rem / 68, icol = rem % 68;
                int cy = quarter * 16 - 1 + ir, cx = icol - 1;
                float v = 0.f;
                if (cy >= 0 && cy < 64 && cx >= 0 && cx < 64) {
                    float wy = rwy[e], wx = rwx[e];
                    float s = rva[e] * (1.f - wy) * (1.f - wx) + rvb[e] * (1.f - wy) * wx +
                              rvc[e] * wy * (1.f - wx) + rvd[e] * wy * wx;
                    v = (s - mean[c]) * istd[c];
                }
                ((unsigned short*)tile)[i] = (unsigned short)rne_bf16(v);
            }
        }
    }
    __syncthreads();
    conv_core(tile, Wb, bc, pooled, 8 + bk, tid);
}

// ---------------------------------------------------------------------------
// Kernel 4: FC [168,256] @ Wf[256,4096] + bf, K-split x4, atomicAdd epilogue.
// grid (16 col-blocks x 256, 7 row-groups x 24, 4 k-splits x 64)
// ---------------------------------------------------------------------------
__global__ __launch_bounds__(256) void fc_kernel(
    const float* __restrict__ pooled, const float* __restrict__ Wf,
    const float* __restrict__ bf, const float* __restrict__ flags,
    float* __restrict__ d_out)
{
    __shared__ __align__(16) float p[24][64];
    const int cb = blockIdx.x, rg = blockIdx.y, kz = blockIdx.z;
    const int tid = threadIdx.x;

    for (int i = tid; i < 24 * 64; i += 256) {
        int r = i >> 6, k = i & 63;
        int R = rg * 24 + r;
        float s = (R < 8) ? (1.f / 16384.f) : (1.f / 256.f);
        p[r][k] = pooled[R * 256 + kz * 64 + k] * s;
    }
    __syncthreads();

    float acc[24];
#pragma unroll
    for (int r = 0; r < 24; ++r) acc[r] = 0.f;

    const int col = cb * 256 + tid;
    const float* wp = Wf + (size_t)(kz * 64) * 4096 + col;
    for (int k = 0; k < 64; k += 4) {
        float w0 = wp[(size_t)(k + 0) * 4096];
        float w1 = wp[(size_t)(k + 1) * 4096];
        float w2 = wp[(size_t)(k + 2) * 4096];
        float w3 = wp[(size_t)(k + 3) * 4096];
#pragma unroll
        for (int r = 0; r < 24; ++r) {
            float4 pv = *(const float4*)&p[r][k];
            acc[r] += pv.x * w0 + pv.y * w1 + pv.z * w2 + pv.w * w3;
        }
    }

    const float bias_on = (kz == 0) ? 1.f : 0.f;
#pragma unroll
    for (int r = 0; r < 24; ++r) {
        int R = rg * 24 + r;
        float v = acc[r] + bias_on * bf[col];
        if (R < 8) {
            atomicAdd(&d_out[FF_OFF + R * 4096 + col], v);
        } else {
            int rr = R - 8;
            if (flags[rr] != 0.f)
                atomicAdd(&d_out[FEAT_OFF + rr * 4096 + col], v);
        }
    }
}

// ---------------------------------------------------------------------------
extern "C" void kernel_launch(void* const* d_in, const int* in_sizes, int n_in,
                              void* d_out, int out_size, void* d_ws, size_t ws_size,
                              hipStream_t stream)
{
    const float* x      = (const float*)d_in[0];
    const float* boxes  = (const float*)d_in[1];
    const float* scores = (const float*)d_in[2];
    const int*   labels = (const int*)d_in[3];
    const float* Wc     = (const float*)d_in[4];
    const float* bc     = (const float*)d_in[5];
    const float* Wf     = (const float*)d_in[6];
    const float* bf     = (const float*)d_in[7];
    float* out = (float*)d_out;

    float* pooled = (float*)d_ws;                       // [168][256] f32 sums
    float* selbox = pooled + POOLED_N;                  // [160][4]
    float* flags  = selbox + SELBOX_N;                  // [160]
    unsigned short* Wb = (unsigned short*)(flags + FLAGS_N);  // [256][192] bf16

    hipMemsetAsync(d_out, 0, (size_t)out_size * sizeof(float), stream);

    prep_kernel<<<K3, 256, 0, stream>>>(Wc, Wb, pooled);
    topk_kernel<<<8, 512, 0, stream>>>(boxes, scores, labels, out, selbox, flags);
    ffconv_mfma<<<dim3(64, 8), 256, 0, stream>>>(x, Wb, bc, pooled);
    cropconv_mfma<<<640, 256, 0, stream>>>(x, Wb, bc, selbox, flags, pooled);
    fc_kernel<<<dim3(16, 7, 4), 256, 0, stream>>>(pooled, Wf, bf, flags, out);
}

// Round 13
// 185.021 us; speedup vs baseline: 1.2337x; 1.2337x over previous
//
#include <hip/hip_runtime.h>
#include <hip/hip_bf16.h>

// Output layout (floats): Objects[8*20*4] @0 | Object_features[8*20*4096] @640
//                        | valid[8*20] @656000 | fullframe_features[8*4096] @656160
#define OBJ_OFF   0
#define FEAT_OFF  640
#define VALID_OFF 656000
#define FF_OFF    656160

// ws layout: pooled[168*256] f32 | selbox[160*4] f32 | flags[160] f32 | Wb[256*192] bf16
#define POOLED_N  (168 * 256)
#define SELBOX_N  (160 * 4)
#define FLAGS_N   (160)
#define K3        192   // padded K: c*64 + r*8 + q  (r,q in 0..7; r==7 or q==7 -> zero weight)

typedef __attribute__((ext_vector_type(8))) short short8v;
typedef __attribute__((ext_vector_type(4))) short short4v;
typedef __attribute__((ext_vector_type(4))) float f32x4;

__device__ __forceinline__ unsigned int rne_bf16(float f) {
    unsigned int u = __float_as_uint(f);
    return (u + 0x7FFFu + ((u >> 16) & 1u)) >> 16;
}

// ---------------------------------------------------------------------------
// Kernel 0: weights -> bf16 padded layout Wb[oc][k'], k' = c*64 + r*8 + q.
// Also zeroes the pooled accumulator (replaces a memset launch).
// ---------------------------------------------------------------------------
__global__ __launch_bounds__(256) void prep_kernel(
    const float* __restrict__ Wc, unsigned short* __restrict__ Wb,
    float* __restrict__ pooled)
{
    int i = blockIdx.x * 256 + threadIdx.x;     // 192 blocks * 256 = 49152
    if (i < POOLED_N) pooled[i] = 0.f;
    int oc = i / K3, k = i % K3;
    int c = k >> 6, r = (k >> 3) & 7, q = k & 7;
    float v = (r < 7 && q < 7) ? Wc[oc * 147 + c * 49 + r * 7 + q] : 0.f;
    Wb[i] = (unsigned short)rne_bf16(v);
}

// ---------------------------------------------------------------------------
// Kernel 1: per-batch masked top-20 selection (LDS reduction — proven correct)
// ---------------------------------------------------------------------------
__global__ __launch_bounds__(512) void topk_kernel(
    const float* __restrict__ boxes, const float* __restrict__ scores,
    const int* __restrict__ labels, float* __restrict__ d_out,
    float* __restrict__ selbox, float* __restrict__ flags)
{
    __shared__ unsigned long long keys[512];
    __shared__ unsigned long long red[512];
    const int b = blockIdx.x, t = threadIdx.x;

    unsigned long long key = 0ULL;
    if (t < 300) {
        float s = scores[b * 300 + t];
        int   l = labels[b * 300 + t];
        bool cls = (l == 2) || (l == 3) || (l == 4) || (l == 6) || (l == 8);
        if (cls && s > 0.8f) {
            key = ((unsigned long long)__float_as_uint(s) << 32) |
                  (unsigned long long)(unsigned int)(~(unsigned int)t);
        }
    }
    keys[t] = key;
    __syncthreads();

    for (int k = 0; k < 20; ++k) {
        red[t] = keys[t];
        __syncthreads();
        for (int s = 256; s > 0; s >>= 1) {
            if (t < s) red[t] = (red[t] > red[t + s]) ? red[t] : red[t + s];
            __syncthreads();
        }
        unsigned long long m = red[0];
        const int slot = b * 20 + k;
        if (m == 0ULL) {
            if (t == 0) {
                d_out[OBJ_OFF + slot * 4 + 0] = 0.f;
                d_out[OBJ_OFF + slot * 4 + 1] = 0.f;
                d_out[OBJ_OFF + slot * 4 + 2] = 0.f;
                d_out[OBJ_OFF + slot * 4 + 3] = 0.f;
                d_out[VALID_OFF + slot] = 0.f;
                selbox[slot * 4 + 0] = 0.f; selbox[slot * 4 + 1] = 0.f;
                selbox[slot * 4 + 2] = 0.f; selbox[slot * 4 + 3] = 0.f;
                flags[slot] = 0.f;
            }
        } else if (keys[t] == m) {  // unique winner (index embedded in key)
            const float bx0 = boxes[(b * 300 + t) * 4 + 0];
            const float by0 = boxes[(b * 300 + t) * 4 + 1];
            const float bx1 = boxes[(b * 300 + t) * 4 + 2];
            const float by1 = boxes[(b * 300 + t) * 4 + 3];
            d_out[OBJ_OFF + slot * 4 + 0] = bx0;
            d_out[OBJ_OFF + slot * 4 + 1] = by0;
            d_out[OBJ_OFF + slot * 4 + 2] = bx1;
            d_out[OBJ_OFF + slot * 4 + 3] = by1;
            d_out[VALID_OFF + slot] = 1.f;
            selbox[slot * 4 + 0] = bx0; selbox[slot * 4 + 1] = by0;
            selbox[slot * 4 + 2] = bx1; selbox[slot * 4 + 3] = by1;
            bool deg = (bx1 <= bx0) || (by1 <= by0);
            flags[slot] = deg ? 0.f : 1.f;
            keys[t] = 0ULL;
        }
        __syncthreads();
    }
}

// ---------------------------------------------------------------------------
// Conv compute: tile in LDS, B-frags streamed from L2 per k-step (transient
// registers only — reg-B hoisting spilled at 128-VGPR cap in round 9).
// A-octet (lane l, frag mf, k-step ks): kq=ks*4+lq; c=kq>>3, rr=kq&7;
// 8 contiguous bf16 at tb[c][mf*4+rr][lr*4..+7]. D: col=lr, row=lq*4+reg.
// Accumulates ReLU'd per-lane pool partials into poolacc (no atomic here).
// ---------------------------------------------------------------------------
__device__ __forceinline__ void conv_compute(
    const unsigned short (&tb)[3][20][68],
    const unsigned short* __restrict__ Wb, const float (&bias)[4],
    float (&poolacc)[4], int n0, int lr, int lq)
{
    f32x4 acc[4][4];
#pragma unroll
    for (int mf = 0; mf < 4; ++mf)
#pragma unroll
        for (int nf = 0; nf < 4; ++nf)
            acc[mf][nf] = (f32x4){0.f, 0.f, 0.f, 0.f};

#pragma unroll
    for (int ks = 0; ks < 6; ++ks) {
        const int kq = ks * 4 + lq;
        const int c = kq >> 3, rr = kq & 7;
        const int koff = ks * 32 + lq * 8;

        short8v a[4], bfr[4];
#pragma unroll
        for (int nf = 0; nf < 4; ++nf)
            bfr[nf] = *(const short8v*)&Wb[(size_t)(n0 + nf * 16 + lr) * K3 + koff];
#pragma unroll
        for (int mf = 0; mf < 4; ++mf) {
            const unsigned short* ap = &tb[c][mf * 4 + rr][lr * 4];
            short4v a0 = *(const short4v*)ap;
            short4v a1 = *(const short4v*)(ap + 4);
            a[mf] = __builtin_shufflevector(a0, a1, 0, 1, 2, 3, 4, 5, 6, 7);
        }
#pragma unroll
        for (int mf = 0; mf < 4; ++mf)
#pragma unroll
            for (int nf = 0; nf < 4; ++nf)
                acc[mf][nf] = __builtin_amdgcn_mfma_f32_16x16x32_bf16(
                    a[mf], bfr[nf], acc[mf][nf], 0, 0, 0);
    }

#pragma unroll
    for (int nf = 0; nf < 4; ++nf) {
        float s = 0.f;
#pragma unroll
        for (int mf = 0; mf < 4; ++mf)
#pragma unroll
            for (int r = 0; r < 4; ++r) {
                float pv = acc[mf][nf][r] + bias[nf];
                s += pv > 0.f ? pv : 0.f;
            }
        poolacc[nf] += s;
    }
}

// Staging helpers for ffconv: issue all 16 loads (raw) / pack+write later.
__device__ __forceinline__ void ff_stage_issue(
    const float* __restrict__ img, int iy0, int ix0, int tid, float (&sv)[16])
{
#pragma unroll
    for (int it = 0; it < 16; ++it) {
        int i = tid + it * 256;
        float v = 0.f;
        if (i < 4080) {
            int c = i / 1360, rem = i % 1360;
            int ir = rem / 68, icol = rem % 68;
            int gy = iy0 + ir, gx = ix0 + icol;
            if (gy >= 0 && gy < 512 && gx >= 0 && gx < 512)
                v = img[((size_t)c * 512 + gy) * 512 + gx];
        }
        sv[it] = v;
    }
}

__device__ __forceinline__ void ff_stage_write(
    unsigned short (&tb)[3][20][68], int iy0, int ix0, int tid,
    const float (&sv)[16], const float* mean, const float* istd)
{
#pragma unroll
    for (int it = 0; it < 16; ++it) {
        int i = tid + it * 256;
        if (i < 4080) {
            int c = i / 1360, rem = i % 1360;
            int ir = rem / 68, icol = rem % 68;
            int gy = iy0 + ir, gx = ix0 + icol;
            bool inb = (gy >= 0 && gy < 512 && gx >= 0 && gx < 512);
            float nv = inb ? (sv[it] - mean[c]) * istd[c] : 0.f;
            ((unsigned short*)tb)[i] = (unsigned short)rne_bf16(nv);
        }
    }
}

// ---------------------------------------------------------------------------
// Kernel 2: fullframe conv. Block handles T=4 row-tiles (double-buffered LDS,
// async-stage split). grid (64 = 8 col-groups x 8 row-blocks, 8 b)
// ---------------------------------------------------------------------------
__global__ __launch_bounds__(256) void ffconv_mfma(
    const float* __restrict__ x, const unsigned short* __restrict__ Wb,
    const float* __restrict__ bc, float* __restrict__ pooled)
{
    __shared__ __align__(16) unsigned short buf[2][3][20][68];
    const int b = blockIdx.y;
    const int tile_x = blockIdx.x & 7, rblk = blockIdx.x >> 3;
    const int tid = threadIdx.x;
    const int w = tid >> 6, l = tid & 63, lr = l & 15, lq = l >> 4;
    const int n0 = w * 64;
    const int ix0 = tile_x * 64 - 1;

    const float mean[3] = {0.485f, 0.456f, 0.406f};
    const float istd[3] = {1.0f / 0.229f, 1.0f / 0.224f, 1.0f / 0.225f};
    const float* __restrict__ img = x + (size_t)b * 3 * 512 * 512;

    float bias[4];
#pragma unroll
    for (int nf = 0; nf < 4; ++nf) bias[nf] = bc[n0 + nf * 16 + lr];

    float poolacc[4] = {0.f, 0.f, 0.f, 0.f};
    float sv[16];

    ff_stage_issue(img, (rblk * 4 + 0) * 16 - 1, ix0, tid, sv);
    ff_stage_write(buf[0], (rblk * 4 + 0) * 16 - 1, ix0, tid, sv, mean, istd);
    __syncthreads();

#pragma unroll
    for (int q = 0; q < 4; ++q) {
        const int cur = q & 1;
        if (q < 3) ff_stage_issue(img, (rblk * 4 + q + 1) * 16 - 1, ix0, tid, sv);
        conv_compute(buf[cur], Wb, bias, poolacc, n0, lr, lq);
        if (q < 3)
            ff_stage_write(buf[cur ^ 1], (rblk * 4 + q + 1) * 16 - 1, ix0, tid, sv, mean, istd);
        __syncthreads();
    }

#pragma unroll
    for (int nf = 0; nf < 4; ++nf) {
        float s = poolacc[nf];
        s += __shfl_down(s, 32);
        s += __shfl_down(s, 16);
        if (l < 16) atomicAdd(&pooled[b * 256 + n0 + nf * 16 + lr], s);
    }
}

// ---------------------------------------------------------------------------
// Kernel 3: crop conv. grid 640 = 160 (b,k) x 4 quarters. Batched bilinear
// staging (32 loads in flight per round). No VGPR cap (r9 spilled at 128).
// ---------------------------------------------------------------------------
__global__ __launch_bounds__(256) void cropconv_mfma(
    const float* __restrict__ x, const unsigned short* __restrict__ Wb,
    const float* __restrict__ bc, const float* __restrict__ selbox,
    const float* __restrict__ flags, float* __restrict__ pooled)
{
    const int bk = blockIdx.x >> 2, quarter = blockIdx.x & 3;
    if (flags[bk] == 0.f) return;          // features get zeroed anyway
    const int b = bk / 20;
    const int tid = threadIdx.x;

    __shared__ __align__(16) unsigned short tile[3][20][68];

    const float bx0 = selbox[bk * 4 + 0], by0 = selbox[bk * 4 + 1];
    const float bx1 = selbox[bk * 4 + 2], by1 = selbox[bk * 4 + 3];
    const float sy = (by1 - by0) * (1.f / 64.f);
    const float sx = (bx1 - bx0) * (1.f / 64.f);

    const float mean[3] = {0.485f, 0.456f, 0.406f};
    const float istd[3] = {1.0f / 0.229f, 1.0f / 0.224f, 1.0f / 0.225f};
    const float* __restrict__ img = x + (size_t)b * 3 * 512 * 512;

#pragma unroll
    for (int rd = 0; rd < 2; ++rd) {
        float rva[8], rvb[8], rvc[8], rvd[8], rwy[8], rwx[8];
#pragma unroll
        for (int e = 0; e < 8; ++e) {
            int i = tid + (rd * 8 + e) * 256;
            float Ia = 0.f, Ib = 0.f, Ic = 0.f, Id = 0.f, wy = 0.f, wx = 0.f;
            if (i < 4080) {
                int c = i / 1360, rem = i % 1360;
                int ir = rem / 68, icol = rem % 68;
                int cy = quarter * 16 - 1 + ir, cx = icol - 1;
                if (cy >= 0 && cy < 64 && cx >= 0 && cx < 64) {
                    float ys = by0 + ((float)cy + 0.5f) * sy;
                    float xs = bx0 + ((float)cx + 0.5f) * sx;
                    float yf = floorf(ys), xf = floorf(xs);
                    wy = ys - yf; wx = xs - xf;
                    int iy0 = min(max((int)yf, 0), 511), iy1 = min(iy0 + 1, 511);
                    int ix0 = min(max((int)xf, 0), 511), ix1 = min(ix0 + 1, 511);
                    const float* ch = img + (size_t)c * 512 * 512;
                    Ia = ch[iy0 * 512 + ix0]; Ib = ch[iy0 * 512 + ix1];
                    Ic = ch[iy1 * 512 + ix0]; Id = ch[iy1 * 512 + ix1];
                }
            }
            rva[e] = Ia; rvb[e] = Ib; rvc[e] = Ic; rvd[e] = Id;
            rwy[e] = wy; rwx[e] = wx;
        }
#pragma unroll
        for (int e = 0; e < 8; ++e) {
            int i = tid + (rd * 8 + e) * 256;
            if (i < 4080) {
                int c = i / 1360, rem = i % 1360;
                int ir = rem / 68, icol = rem % 68;
                int cy = quarter * 16 - 1 + ir, cx = icol - 1;
                float v = 0.f;
                if (cy >= 0 && cy < 64 && cx >= 0 && cx < 64) {
                    float wy = rwy[e], wx = rwx[e];
                    float s = rva[e] * (1.f - wy) * (1.f - wx) + rvb[e] * (1.f - wy) * wx +
                              rvc[e] * wy * (1.f - wx) + rvd[e] * wy * wx;
                    v = (s - mean[c]) * istd[c];
                }
                ((unsigned short*)tile)[i] = (unsigned short)rne_bf16(v);
            }
        }
    }
    __syncthreads();

    const int w = tid >> 6, l = tid & 63, lr = l & 15, lq = l >> 4;
    const int n0 = w * 64;
    float bias[4];
#pragma unroll
    for (int nf = 0; nf < 4; ++nf) bias[nf] = bc[n0 + nf * 16 + lr];
    float poolacc[4] = {0.f, 0.f, 0.f, 0.f};

    conv_compute(tile, Wb, bias, poolacc, n0, lr, lq);

#pragma unroll
    for (int nf = 0; nf < 4; ++nf) {
        float s = poolacc[nf];
        s += __shfl_down(s, 32);
        s += __shfl_down(s, 16);
        if (l < 16) atomicAdd(&pooled[(8 + bk) * 256 + n0 + nf * 16 + lr], s);
    }
}

// ---------------------------------------------------------------------------
// Kernel 4: FC [168,256] @ Wf[256,4096] + bf, K-split x4, atomicAdd epilogue.
// grid (16 col-blocks x 256, 14 row-groups x 12, 4 k-splits x 64)
// ---------------------------------------------------------------------------
__global__ __launch_bounds__(256) void fc_kernel(
    const float* __restrict__ pooled, const float* __restrict__ Wf,
    const float* __restrict__ bf, const float* __restrict__ flags,
    float* __restrict__ d_out)
{
    __shared__ __align__(16) float p[12][64];
    const int cb = blockIdx.x, rg = blockIdx.y, kz = blockIdx.z;
    const int tid = threadIdx.x;

    for (int i = tid; i < 12 * 64; i += 256) {
        int r = i >> 6, k = i & 63;
        int R = rg * 12 + r;
        float s = (R < 8) ? (1.f / 16384.f) : (1.f / 256.f);
        p[r][k] = pooled[R * 256 + kz * 64 + k] * s;
    }
    __syncthreads();

    float acc[12];
#pragma unroll
    for (int r = 0; r < 12; ++r) acc[r] = 0.f;

    const int col = cb * 256 + tid;
    const float* wp = Wf + (size_t)(kz * 64) * 4096 + col;
    for (int k = 0; k < 64; k += 4) {
        float w0 = wp[(size_t)(k + 0) * 4096];
        float w1 = wp[(size_t)(k + 1) * 4096];
        float w2 = wp[(size_t)(k + 2) * 4096];
        float w3 = wp[(size_t)(k + 3) * 4096];
#pragma unroll
        for (int r = 0; r < 12; ++r) {
            float4 pv = *(const float4*)&p[r][k];
            acc[r] += pv.x * w0 + pv.y * w1 + pv.z * w2 + pv.w * w3;
        }
    }

    const float bias_on = (kz == 0) ? 1.f : 0.f;
#pragma unroll
    for (int r = 0; r < 12; ++r) {
        int R = rg * 12 + r;
        float v = acc[r] + bias_on * bf[col];
        if (R < 8) {
            atomicAdd(&d_out[FF_OFF + R * 4096 + col], v);
        } else {
            int rr = R - 8;
            if (flags[rr] != 0.f)
                atomicAdd(&d_out[FEAT_OFF + rr * 4096 + col], v);
        }
    }
}

// ---------------------------------------------------------------------------
extern "C" void kernel_launch(void* const* d_in, const int* in_sizes, int n_in,
                              void* d_out, int out_size, void* d_ws, size_t ws_size,
                              hipStream_t stream)
{
    const float* x      = (const float*)d_in[0];
    const float* boxes  = (const float*)d_in[1];
    const float* scores = (const float*)d_in[2];
    const int*   labels = (const int*)d_in[3];
    const float* Wc     = (const float*)d_in[4];
    const float* bc     = (const float*)d_in[5];
    const float* Wf     = (const float*)d_in[6];
    const float* bf     = (const float*)d_in[7];
    float* out = (float*)d_out;

    float* pooled = (float*)d_ws;                       // [168][256] f32 sums
    float* selbox = pooled + POOLED_N;                  // [160][4]
    float* flags  = selbox + SELBOX_N;                  // [160]
    unsigned short* Wb = (unsigned short*)(flags + FLAGS_N);  // [256][192] bf16

    hipMemsetAsync(d_out, 0, (size_t)out_size * sizeof(float), stream);

    prep_kernel<<<K3, 256, 0, stream>>>(Wc, Wb, pooled);
    topk_kernel<<<8, 512, 0, stream>>>(boxes, scores, labels, out, selbox, flags);
    ffconv_mfma<<<dim3(64, 8), 256, 0, stream>>>(x, Wb, bc, pooled);
    cropconv_mfma<<<640, 256, 0, stream>>>(x, Wb, bc, selbox, flags, pooled);
    fc_kernel<<<dim3(16, 14, 4), 256, 0, stream>>>(pooled, Wf, bf, flags, out);
}